// Round 1
// baseline (435.475 us; speedup 1.0000x reference)
//
#include <hip/hip_runtime.h>
#include <hip/hip_bf16.h>
#include <math.h>

#define D 128

__device__ __forceinline__ float gelu_exact(float x) {
    return 0.5f * x * (1.0f + erff(x * 0.70710678118654752440f));
}
__device__ __forceinline__ float elu1(float x) {
    return x > 0.f ? x : expm1f(x);
}

// ---------------------------------------------------------------------------
// Detect whether edge_index buffer is int64 (high dwords all zero) or int32.
// flag[0] = 1 -> int64 layout, 0 -> int32 layout.
__global__ void detect64_kernel(const int* __restrict__ p, int* __restrict__ flag, int npairs) {
    __shared__ int any;
    if (threadIdx.x == 0) any = 0;
    __syncthreads();
    for (int i = threadIdx.x; i < npairs; i += blockDim.x) {
        if (p[2 * i + 1] != 0) any = 1;   // benign race
    }
    __syncthreads();
    if (threadIdx.x == 0) flag[0] = any ? 0 : 1;
}

// ---------------------------------------------------------------------------
// Count in-degree (targets = col = elements [E, 2E) of edge_index)
__global__ void count_deg_kernel(const int* __restrict__ ep, const int* __restrict__ flag,
                                 int* __restrict__ deg, int E) {
    int e = blockIdx.x * blockDim.x + threadIdx.x;
    if (e >= E) return;
    int mode = flag[0];
    int c = mode ? ep[2 * (E + e)] : ep[E + e];
    atomicAdd(&deg[c], 1);
}

// ---------------------------------------------------------------------------
// Exclusive scan of deg[0..n) -> rowptr[0..n]. Single block, 1024 threads.
__global__ __launch_bounds__(1024) void scan_exclusive_kernel(const int* __restrict__ deg,
                                                              int* __restrict__ rowptr, int n) {
    __shared__ int wsum[16];
    __shared__ int carry_s;
    const int tid = threadIdx.x;
    const int lane = tid & 63;
    const int wv = tid >> 6;
    if (tid == 0) carry_s = 0;
    __syncthreads();
    for (int base = 0; base < n; base += 1024) {
        int idx = base + tid;
        int v = (idx < n) ? deg[idx] : 0;
        int s = v;
        #pragma unroll
        for (int off = 1; off < 64; off <<= 1) {
            int t = __shfl_up(s, off);
            if (lane >= off) s += t;
        }
        if (lane == 63) wsum[wv] = s;
        int c0 = carry_s;
        __syncthreads();
        if (wv == 0) {
            int ws = (lane < 16) ? wsum[lane] : 0;
            #pragma unroll
            for (int off = 1; off < 16; off <<= 1) {
                int t = __shfl_up(ws, off);
                if (lane >= off) ws += t;
            }
            if (lane < 16) wsum[lane] = ws;
        }
        __syncthreads();
        int woff = (wv == 0) ? 0 : wsum[wv - 1];
        if (idx < n) rowptr[idx] = c0 + woff + s - v;
        int total = wsum[15];
        __syncthreads();
        if (tid == 0) carry_s = c0 + total;
        __syncthreads();
    }
    if (threadIdx.x == 0) rowptr[n] = carry_s;
}

// ---------------------------------------------------------------------------
__global__ void dinv_kernel(const int* __restrict__ deg, float* __restrict__ dinv, int n) {
    int i = blockIdx.x * blockDim.x + threadIdx.x;
    if (i >= n) return;
    dinv[i] = 1.0f / sqrtf((float)(deg[i] + 1));   // +1 self loop
}

// ---------------------------------------------------------------------------
// Fill CSR: for each edge, append src row under its target's bucket.
__global__ void fill_csr_kernel(const int* __restrict__ ep, const int* __restrict__ flag,
                                const int* __restrict__ rowptr, int* __restrict__ cursor,
                                int* __restrict__ csr, int E) {
    int e = blockIdx.x * blockDim.x + threadIdx.x;
    if (e >= E) return;
    int mode = flag[0];
    int r = mode ? ep[2 * e] : ep[e];
    int c = mode ? ep[2 * (E + e)] : ep[E + e];
    int pos = atomicAdd(&cursor[c], 1);
    csr[rowptr[c] + pos] = r;
}

// ---------------------------------------------------------------------------
// Transpose the three 128x128 weights into WT (k-major) for coalesced GEMM staging.
__global__ void transpose3_kernel(const float* __restrict__ W1, const float* __restrict__ Wt2,
                                  const float* __restrict__ W2, float* __restrict__ WT) {
    int idx = blockIdx.x * blockDim.x + threadIdx.x;   // 0 .. 3*16384
    int m = idx >> 14;
    int flat = idx & 16383;
    int j = flat >> 7, k = flat & 127;
    const float* src = (m == 0) ? W1 : ((m == 1) ? Wt2 : W2);
    WT[m * 16384 + k * 128 + j] = src[flat];
}

// ---------------------------------------------------------------------------
// GEMM: out[r][j] = sum_k A[r][k] * W[j][k]   (WT is W transposed: WT[k][j])
// MODE 0: A = Ain (plain)
// MODE 1: A[r][d] = gelu(t[r]*wt1[d] + bt1[d]);  out += bias1[j] + bias2[j]
// MODE 2: A = elu(Ain)
template <int MODE>
__global__ __launch_bounds__(256) void gemm128_kernel(
    const float* __restrict__ Ain, const int* __restrict__ tvec,
    const float* __restrict__ wt1, const float* __restrict__ bt1,
    const float* __restrict__ WT,
    const float* __restrict__ bias1, const float* __restrict__ bias2,
    float* __restrict__ out, int n) {
    __shared__ float Ash[32][132];
    __shared__ float Wsh[128][132];
    const int tid = threadIdx.x;
    const int r0 = blockIdx.x * 32;

    // stage WT -> Wsh (row k holds W[:,k] over j, padded stride 132)
    #pragma unroll
    for (int rep = 0; rep < 16; ++rep) {
        int flat = rep * 1024 + tid * 4;
        int k = flat >> 7, j = flat & 127;
        float4 w = *(const float4*)(WT + flat);
        *(float4*)&Wsh[k][j] = w;
    }
    // stage A -> Ash
    if (MODE == 1) {
        #pragma unroll
        for (int rep = 0; rep < 4; ++rep) {
            int flat = rep * 1024 + tid * 4;
            int r = flat >> 7, d = flat & 127;
            int rr = r0 + r;
            float tv = (rr < n) ? (float)tvec[rr] : 0.f;
            float4 w1 = *(const float4*)(wt1 + d);
            float4 bv = *(const float4*)(bt1 + d);
            float4 g;
            g.x = gelu_exact(fmaf(tv, w1.x, bv.x));
            g.y = gelu_exact(fmaf(tv, w1.y, bv.y));
            g.z = gelu_exact(fmaf(tv, w1.z, bv.z));
            g.w = gelu_exact(fmaf(tv, w1.w, bv.w));
            *(float4*)&Ash[r][d] = g;
        }
    } else {
        #pragma unroll
        for (int rep = 0; rep < 4; ++rep) {
            int flat = rep * 1024 + tid * 4;
            int r = flat >> 7, k = flat & 127;
            int rr = r0 + r;
            float4 a = make_float4(0.f, 0.f, 0.f, 0.f);
            if (rr < n) a = *(const float4*)(Ain + (size_t)rr * D + k);
            if (MODE == 2) {
                a.x = elu1(a.x); a.y = elu1(a.y); a.z = elu1(a.z); a.w = elu1(a.w);
            }
            *(float4*)&Ash[r][k] = a;
        }
    }
    __syncthreads();

    const int tx = tid & 31, ty = tid >> 5;
    float acc[4][4];
    #pragma unroll
    for (int i = 0; i < 4; ++i)
        #pragma unroll
        for (int j = 0; j < 4; ++j) acc[i][j] = 0.f;

    for (int k0 = 0; k0 < 128; k0 += 4) {
        float4 a[4], w[4];
        #pragma unroll
        for (int i = 0; i < 4; ++i) a[i] = *(const float4*)&Ash[ty * 4 + i][k0];
        #pragma unroll
        for (int kk = 0; kk < 4; ++kk) w[kk] = *(const float4*)&Wsh[k0 + kk][tx * 4];
        #pragma unroll
        for (int i = 0; i < 4; ++i) {
            float ax = a[i].x, ay = a[i].y, az = a[i].z, aw = a[i].w;
            acc[i][0] = fmaf(ax, w[0].x, fmaf(ay, w[1].x, fmaf(az, w[2].x, fmaf(aw, w[3].x, acc[i][0]))));
            acc[i][1] = fmaf(ax, w[0].y, fmaf(ay, w[1].y, fmaf(az, w[2].y, fmaf(aw, w[3].y, acc[i][1]))));
            acc[i][2] = fmaf(ax, w[0].z, fmaf(ay, w[1].z, fmaf(az, w[2].z, fmaf(aw, w[3].z, acc[i][2]))));
            acc[i][3] = fmaf(ax, w[0].w, fmaf(ay, w[1].w, fmaf(az, w[2].w, fmaf(aw, w[3].w, acc[i][3]))));
        }
    }

    float4 badd = make_float4(0.f, 0.f, 0.f, 0.f);
    if (MODE == 1) {
        float4 b1v = *(const float4*)(bias1 + tx * 4);
        float4 b2v = *(const float4*)(bias2 + tx * 4);
        badd.x = b1v.x + b2v.x; badd.y = b1v.y + b2v.y;
        badd.z = b1v.z + b2v.z; badd.w = b1v.w + b2v.w;
    }
    #pragma unroll
    for (int i = 0; i < 4; ++i) {
        int rr = r0 + ty * 4 + i;
        if (rr < n) {
            float4 o;
            o.x = acc[i][0] + badd.x;
            o.y = acc[i][1] + badd.y;
            o.z = acc[i][2] + badd.z;
            o.w = acc[i][3] + badd.w;
            *(float4*)(out + (size_t)rr * D + tx * 4) = o;
        }
    }
}

// ---------------------------------------------------------------------------
// Gather-aggregation: one wave per node.
// dst[i] (+)= dinv[i] * ( dinv[i]*xw[i] + sum_{r in in(i)} dinv[r]*xw[r] )  [+ bias]
__global__ __launch_bounds__(256) void gather_kernel(
    const float* __restrict__ xw, const float* __restrict__ dinv,
    const int* __restrict__ rowptr, const int* __restrict__ csr,
    float* __restrict__ dst, const float* __restrict__ bias, int accumulate, int n) {
    int wid = (blockIdx.x * 256 + threadIdx.x) >> 6;
    if (wid >= n) return;
    int lane = threadIdx.x & 63;
    float di = dinv[wid];
    float2 v = *(const float2*)(xw + (size_t)wid * D + lane * 2);
    float sx = di * v.x, sy = di * v.y;
    int e0 = rowptr[wid], e1 = rowptr[wid + 1];
    for (int e = e0; e < e1; ++e) {
        int r = csr[e];
        float w = dinv[r];
        float2 u = *(const float2*)(xw + (size_t)r * D + lane * 2);
        sx = fmaf(w, u.x, sx);
        sy = fmaf(w, u.y, sy);
    }
    float* d = dst + (size_t)wid * D + lane * 2;
    if (accumulate) {
        d[0] += di * sx;
        d[1] += di * sy;
    } else {
        float2 b = *(const float2*)(bias + lane * 2);
        d[0] = di * sx + b.x;
        d[1] = di * sy + b.y;
    }
}

// ---------------------------------------------------------------------------
extern "C" void kernel_launch(void* const* d_in, const int* in_sizes, int n_in,
                              void* d_out, int out_size, void* d_ws, size_t ws_size,
                              hipStream_t stream) {
    const float* z   = (const float*)d_in[0];
    const int*   ep  = (const int*)d_in[1];
    const int*   t   = (const int*)d_in[2];
    const float* Wt1 = (const float*)d_in[3];
    const float* bt1 = (const float*)d_in[4];
    const float* Wt2 = (const float*)d_in[5];
    const float* bt2 = (const float*)d_in[6];
    const float* W1  = (const float*)d_in[7];
    const float* b1  = (const float*)d_in[8];
    const float* W2  = (const float*)d_in[9];
    const float* b2  = (const float*)d_in[10];
    float* out = (float*)d_out;

    const int N = in_sizes[0] / D;     // 50000
    const int E = in_sizes[1] / 2;     // 640000

    size_t off = 0;
    auto carve = [&](size_t nbytes) -> void* {
        void* p = (void*)((char*)d_ws + off);
        off += (nbytes + 255) & ~(size_t)255;
        return p;
    };
    int*   flag   = (int*)carve(256);
    int*   deg    = (int*)carve((size_t)N * 4);
    int*   cursor = (int*)carve((size_t)N * 4);
    int*   rowptr = (int*)carve((size_t)(N + 1) * 4);
    float* dinv   = (float*)carve((size_t)N * 4);
    int*   csr    = (int*)carve((size_t)E * 4);
    float* WT     = (float*)carve((size_t)3 * 16384 * 4);
    float* xw     = (float*)carve((size_t)N * D * 4);
    float* acc    = (float*)carve((size_t)N * D * 4);
    (void)ws_size; (void)n_in; (void)out_size;

    const float* WT1  = WT;
    const float* WTt2 = WT + 16384;
    const float* WT2  = WT + 2 * 16384;

    hipMemsetAsync(deg, 0, (size_t)N * 4, stream);
    hipMemsetAsync(cursor, 0, (size_t)N * 4, stream);

    detect64_kernel<<<1, 256, 0, stream>>>(ep, flag, 2000);
    transpose3_kernel<<<192, 256, 0, stream>>>(W1, Wt2, W2, WT);
    count_deg_kernel<<<(E + 255) / 256, 256, 0, stream>>>(ep, flag, deg, E);
    scan_exclusive_kernel<<<1, 1024, 0, stream>>>(deg, rowptr, N);
    dinv_kernel<<<(N + 255) / 256, 256, 0, stream>>>(deg, dinv, N);
    fill_csr_kernel<<<(E + 255) / 256, 256, 0, stream>>>(ep, flag, rowptr, cursor, csr, E);

    int gemm_blocks = (N + 31) / 32;
    // xw = z @ W1.T
    gemm128_kernel<0><<<gemm_blocks, 256, 0, stream>>>(z, nullptr, nullptr, nullptr,
                                                       WT1, nullptr, nullptr, xw, N);
    // acc = t_emb + bt2 + b1
    gemm128_kernel<1><<<gemm_blocks, 256, 0, stream>>>(nullptr, t, Wt1, bt1,
                                                       WTt2, bt2, b1, acc, N);
    // acc += normalized aggregation of xw  (conv1 without bias)
    gather_kernel<<<(N * 64 + 255) / 256, 256, 0, stream>>>(xw, dinv, rowptr, csr,
                                                            acc, nullptr, 1, N);
    // xw = elu(acc) @ W2.T
    gemm128_kernel<2><<<gemm_blocks, 256, 0, stream>>>(acc, nullptr, nullptr, nullptr,
                                                       WT2, nullptr, nullptr, xw, N);
    // out = normalized aggregation of xw + b2
    gather_kernel<<<(N * 64 + 255) / 256, 256, 0, stream>>>(xw, dinv, rowptr, csr,
                                                            out, b2, 0, N);
}